// Round 6
// baseline (68.068 us; speedup 1.0000x reference)
//
#include <hip/hip_runtime.h>

#define CRGB 64
#define CEV  32
#define CIN  96
#define MID  32
#define HH   256
#define WW   256
#define HW   (HH*WW)

// tile geometry: block = 256 threads = 8x32 pixels, halo tile 10x34
#define TLH 8
#define TLW 32
#define SRH 10
#define SRW 34
#define SPX (SRH*SRW)   // 340 pixels, 64 ch f16 = 43520 B LDS

typedef _Float16 f16x8 __attribute__((ext_vector_type(8)));
typedef _Float16 f16x4 __attribute__((ext_vector_type(4)));
typedef float    f32x4 __attribute__((ext_vector_type(4)));

// ws layout (bytes):
//   [0,     36864) : W2f f16 A-frag-linear, k-dim permuted: kappa = g*8+mh*4+r <-> m = mh*16+g*4+r
//   [36864, 43008) : W1f f16 A-frag-linear (natural k-order)
//   [43008, 45312) : b2p f32 [(cg*9+ij)*16 + cc]
#define WS_W2F 0
#define WS_W1F 36864
#define WS_B2P 43008

__global__ __launch_bounds__(256) void prep_kernel(
    const float* __restrict__ W1, const float* __restrict__ W2,
    const float* __restrict__ b2, char* __restrict__ ws)
{
    _Float16* W2f = (_Float16*)(ws + WS_W2F);
    _Float16* W1f = (_Float16*)(ws + WS_W1F);
    float*    b2p = (float*)(ws + WS_B2P);
    const int idx = blockIdx.x * 256 + threadIdx.x;
    if (idx < 18432) {
        const int e   = idx & 7;
        const int ln  = (idx >> 3) & 63;
        const int t   = idx >> 9;             // cg*9+ij, 0..35
        const int ij  = t % 9, cg = t / 9;
        const int c   = cg * 16 + (ln & 15);  // A row = out channel within cg
        const int kap = (ln >> 4) * 8 + e;    // kappa
        const int m   = ((kap >> 2) & 1) * 16 + (kap >> 3) * 4 + (kap & 3);
        W2f[idx] = (_Float16)W2[(c * 9 + ij) * MID + m];
    }
    if (idx < 3072) {
        const int e  = idx & 7;
        const int ln = (idx >> 3) & 63;
        const int t  = idx >> 9;              // ks*2+mh, 0..5
        const int ks = t >> 1, mh = t & 1;
        const int m  = mh * 16 + (ln & 15);
        const int k  = ks * 32 + (ln >> 4) * 8 + e;
        W1f[idx] = (_Float16)W1[m * CIN + k];
    }
    if (idx < 576) {
        const int cc = idx & 15;
        const int t  = idx >> 4;
        const int ij = t % 9, cg = t / 9;
        b2p[idx] = b2[(cg * 16 + cc) * 9 + ij];
    }
}

// Block = 256 threads (4 waves) = 8x32 px tile, all 64 out channels.
// Wave w owns rows {2w, 2w+1}. One barrier total. LDS swizzle: 16B chunk
// q of pixel p stored at unit p*8 + (q ^ (p&7)).
__global__ __launch_bounds__(256, 4) void fusion_mfma3(
    const float* __restrict__ rgb, const float* __restrict__ ev,
    const float* __restrict__ b1, const char* __restrict__ ws,
    float* __restrict__ out)
{
    __shared__ __align__(16) _Float16 srgb[SPX * 64];   // 43520 B

    const int tid  = threadIdx.x;
    const int wave = tid >> 6;
    const int lane = tid & 63;
    const int l15  = lane & 15;
    const int g    = lane >> 4;

    const int bx = blockIdx.x;
    const int tc = bx & 7, tr = (bx >> 3) & 31, b = bx >> 8;
    const int px0 = tc * TLW, py0 = tr * TLH;

    const float* rgbP = rgb + (size_t)b * CRGB * HW;
    const float* evP  = ev  + (size_t)b * CEV  * HW;
    float*       outP = out + (size_t)b * CRGB * HW;

    const _Float16* W2f = (const _Float16*)(ws + WS_W2F);
    const _Float16* W1f = (const _Float16*)(ws + WS_W1F);
    const float*    b2p = (const float*)(ws + WS_B2P);

    // ---- stage full rgb halo tile (64 ch, reflect) as f16, swizzled ---------
    f16x8* sv = (f16x8*)srgb;
    for (int p = tid; p < SPX; p += 256) {
        const int row = p / SRW;
        const int col = p - row * SRW;
        int gy = py0 - 1 + row; gy = gy < 0 ? 1 : (gy > HH - 1 ? HH - 2 : gy);
        int gx = px0 - 1 + col; gx = gx < 0 ? 1 : (gx > WW - 1 ? WW - 2 : gx);
        const float* src = rgbP + (size_t)gy * WW + gx;
        const int pb = p * 8, ps = p & 7;
#pragma unroll
        for (int q = 0; q < 8; ++q) {
            f16x8 v;
#pragma unroll
            for (int e = 0; e < 8; ++e)
                v[e] = (_Float16)src[(size_t)(q * 8 + e) * HW];
            sv[pb + (q ^ ps)] = v;
        }
    }

    // conv1 A-frags + biases + ev B-frags (independent of LDS staging;
    // their HBM latency hides under the staging drain)
    f16x8 a1[6];
#pragma unroll
    for (int t = 0; t < 6; ++t)
        a1[t] = ((const f16x8*)W1f)[t * 64 + lane];
    const f32x4 b1v0 = *(const f32x4*)(b1 + g * 4);
    const f32x4 b1v1 = *(const f32x4*)(b1 + 16 + g * 4);

    f16x8 bk2[4];
#pragma unroll
    for (int st = 0; st < 4; ++st) {
        const int row_l = wave * 2 + (st & 1);
        const int col   = (st >> 1) * 16 + l15;
        const float* esrc = evP + (size_t)(py0 + row_l) * WW + (px0 + col);
#pragma unroll
        for (int e = 0; e < 8; ++e)
            bk2[st][e] = (_Float16)esrc[(size_t)(g * 8 + e) * HW];
    }

    __syncthreads();

    // ---- conv1 via MFMA: produce conv2 B-frags entirely in registers --------
    f16x8 bfr[4];
#pragma unroll
    for (int st = 0; st < 4; ++st) {
        const int row_l = wave * 2 + (st & 1);
        const int col   = (st >> 1) * 16 + l15;
        const int pt    = (row_l + 1) * SRW + col + 1;
        const f16x8 bk0 = sv[pt * 8 + ( g      ^ (pt & 7))];
        const f16x8 bk1 = sv[pt * 8 + ((4 + g) ^ (pt & 7))];
        f32x4 d0 = {0.f, 0.f, 0.f, 0.f}, d1 = {0.f, 0.f, 0.f, 0.f};
        d0 = __builtin_amdgcn_mfma_f32_16x16x32_f16(a1[0], bk0, d0, 0, 0, 0);
        d1 = __builtin_amdgcn_mfma_f32_16x16x32_f16(a1[1], bk0, d1, 0, 0, 0);
        d0 = __builtin_amdgcn_mfma_f32_16x16x32_f16(a1[2], bk1, d0, 0, 0, 0);
        d1 = __builtin_amdgcn_mfma_f32_16x16x32_f16(a1[3], bk1, d1, 0, 0, 0);
        d0 = __builtin_amdgcn_mfma_f32_16x16x32_f16(a1[4], bk2[st], d0, 0, 0, 0);
        d1 = __builtin_amdgcn_mfma_f32_16x16x32_f16(a1[5], bk2[st], d1, 0, 0, 0);
        // bias + relu + pack: e = mh*4+r -> kappa = g*8+mh*4+r (matches W2f perm)
        f16x8 bf;
#pragma unroll
        for (int r = 0; r < 4; ++r) {
            float v0 = d0[r] + b1v0[r]; v0 = v0 > 0.f ? v0 : 0.f;
            float v1 = d1[r] + b1v1[r]; v1 = v1 > 0.f ? v1 : 0.f;
            bf[r]     = (_Float16)v0;
            bf[4 + r] = (_Float16)v1;
        }
        bfr[st] = bf;
    }

    // ---- conv2 (MFMA, bias via C-init) + apply from LDS ---------------------
    for (int cg = 0; cg < 4; ++cg) {
        f16x8 a2[9];
        f32x4 ci[9];
#pragma unroll
        for (int ij = 0; ij < 9; ++ij) {
            a2[ij] = ((const f16x8*)W2f)[(cg * 9 + ij) * 64 + lane];
            ci[ij] = *(const f32x4*)(b2p + (cg * 9 + ij) * 16 + g * 4);
        }
        const int qs  = cg * 2 + (g >> 1);   // 16B chunk of this lane's ch-quad
        const int sub = g & 1;               // 8B half within chunk
#pragma unroll
        for (int st = 0; st < 4; ++st) {
            const int row_l = wave * 2 + (st & 1);
            const int col   = (st >> 1) * 16 + l15;
            float acc0 = 0.f, acc1 = 0.f, acc2 = 0.f, acc3 = 0.f;
#pragma unroll
            for (int ij = 0; ij < 9; ++ij) {
                const f32x4 d = __builtin_amdgcn_mfma_f32_16x16x32_f16(a2[ij], bfr[st], ci[ij], 0, 0, 0);
                const int pt = (row_l + ij / 3) * SRW + col + (ij % 3);
                const f16x4 pv = ((const f16x4*)srgb)[(pt * 8 + (qs ^ (pt & 7))) * 2 + sub];
                acc0 = fmaf(d[0], (float)pv[0], acc0);
                acc1 = fmaf(d[1], (float)pv[1], acc1);
                acc2 = fmaf(d[2], (float)pv[2], acc2);
                acc3 = fmaf(d[3], (float)pv[3], acc3);
            }
            float* op = outP + (size_t)(cg * 16 + g * 4) * HW
                             + (size_t)(py0 + row_l) * WW + (px0 + col);
            op[0]      = acc0;
            op[HW]     = acc1;
            op[2 * HW] = acc2;
            op[3 * HW] = acc3;
        }
    }
}

extern "C" void kernel_launch(void* const* d_in, const int* in_sizes, int n_in,
                              void* d_out, int out_size, void* d_ws, size_t ws_size,
                              hipStream_t stream) {
    const float* rgb = (const float*)d_in[0];
    const float* ev  = (const float*)d_in[1];
    const float* W1p = (const float*)d_in[2];
    const float* b1p = (const float*)d_in[3];
    const float* W2p = (const float*)d_in[4];
    const float* b2p = (const float*)d_in[5];
    float* out = (float*)d_out;
    char* ws = (char*)d_ws;

    hipLaunchKernelGGL(prep_kernel, dim3(72), dim3(256), 0, stream, W1p, W2p, b2p, ws);

    const int B = in_sizes[0] / (CRGB * HW);   // = 4
    hipLaunchKernelGGL(fusion_mfma3, dim3(B * 256), dim3(256), 0, stream,
                       rgb, ev, b1p, ws, out);
}